// Round 4
// baseline (89.404 us; speedup 1.0000x reference)
//
#include <hip/hip_runtime.h>

// Mixture-of-64-tiny-experts, fp32.
// R3: weight-fetch restructure. All per-subnet params repacked (prep kernel)
// into contiguous 48-float blocks in d_ws -> main loop loads 12 x float4
// per subnet (was ~45 scattered scalar loads + addressing). Math unchanged.

#define NSUB 64

// tanhshrink(a) = a - tanh(a) = (a-1) + 2/(exp2(2*log2e*a)+1)
__device__ __forceinline__ float tanhshrink_fast(float a) {
    float e = __builtin_amdgcn_exp2f(a * 2.8853900817779268f);
    float r = __builtin_amdgcn_rcpf(e + 1.0f);
    return fmaf(2.0f, r, a - 1.0f);
}

__device__ __forceinline__ float tanh_fast(float a) {
    float e = __builtin_amdgcn_exp2f(a * 2.8853900817779268f);
    float r = __builtin_amdgcn_rcpf(e + 1.0f);
    return fmaf(-2.0f, r, 1.0f);
}

__device__ __forceinline__ float fast_exp(float x) {
    return __builtin_amdgcn_exp2f(x * 1.4426950408889634f);
}

// Pack per-subnet params into 48-float blocks:
// [0:24) W1 (4x6 row-major) | [24:28) b1 | [28:36) W2 (2x4) | [36:38) b2
// [38:44) Gw2 | [44] Gb2 | [45:48) pad
__global__ void pack_kernel(const float* __restrict__ W1, const float* __restrict__ b1,
                            const float* __restrict__ W2, const float* __restrict__ b2,
                            const float* __restrict__ Gw2, const float* __restrict__ Gb2,
                            float* __restrict__ ws)
{
    int s = threadIdx.x;
    if (s >= NSUB) return;
    float* f = ws + s * 48;
    for (int i = 0; i < 24; ++i) f[i]      = W1[s * 24 + i];
    for (int i = 0; i < 4;  ++i) f[24 + i] = b1[s * 4 + i];
    for (int i = 0; i < 8;  ++i) f[28 + i] = W2[s * 8 + i];
    for (int i = 0; i < 2;  ++i) f[36 + i] = b2[s * 2 + i];
    for (int i = 0; i < 6;  ++i) f[38 + i] = Gw2[s * 6 + i];
    f[44] = Gb2[s];
    f[45] = 0.f; f[46] = 0.f; f[47] = 0.f;
}

__global__ __launch_bounds__(256) void moe_kernel(
    const float* __restrict__ x,
    const float* __restrict__ wpack,   // d_ws, packed weights
    const float* __restrict__ Gw1, const float* __restrict__ Gb1,
    float* __restrict__ out)
{
    int t = blockIdx.x * blockDim.x + threadIdx.x;

    const float2* xv = (const float2*)(x + (long)t * 6);
    float2 p0 = xv[0];
    float2 p1 = xv[1];
    float2 p2 = xv[2];
    float xa[6] = {p0.x, p0.y, p1.x, p1.y, p2.x, p2.y};

    // ---- gating hidden: g = tanhshrink(Gw1 @ x + Gb1) ----
    float ga[6];
#pragma unroll
    for (int j = 0; j < 6; ++j) {
        float sa = Gb1[j];
#pragma unroll
        for (int i = 0; i < 6; ++i)
            sa = fmaf(Gw1[j * 6 + i], xa[i], sa);
        ga[j] = tanhshrink_fast(sa);
    }

    // ---- subnet loop: 12 x float4 packed weight loads per subnet ----
    float acc0 = 0.f, acc1 = 0.f, accE = 0.f;

#pragma unroll 2
    for (int s = 0; s < NSUB; ++s) {
        const float4* wp = (const float4*)(wpack + s * 48);
        float4 v[12];
#pragma unroll
        for (int k = 0; k < 12; ++k) v[k] = wp[k];
        const float* f = (const float*)v;   // constant-index access only

        float h[4];
#pragma unroll
        for (int j = 0; j < 4; ++j) {
            float sa = f[24 + j];
#pragma unroll
            for (int i = 0; i < 6; ++i)
                sa = fmaf(f[j * 6 + i], xa[i], sa);
            h[j] = tanhshrink_fast(sa);
        }

        float o0 = f[36], o1 = f[37];
#pragma unroll
        for (int j = 0; j < 4; ++j) {
            o0 = fmaf(f[28 + j], h[j], o0);
            o1 = fmaf(f[32 + j], h[j], o1);
        }
        o0 = tanh_fast(o0);
        o1 = tanh_fast(o1);

        float la = f[44];
#pragma unroll
        for (int j = 0; j < 6; ++j)
            la = fmaf(f[38 + j], ga[j], la);

        float ea = fast_exp(la);   // logits small; no max-subtract needed
        accE += ea;
        acc0 = fmaf(ea, o0, acc0);
        acc1 = fmaf(ea, o1, acc1);
    }

    float ra = __builtin_amdgcn_rcpf(accE);
    float2 r;
    r.x = acc0 * ra;
    r.y = acc1 * ra;
    ((float2*)&out[(long)t * 2])[0] = r;
}

extern "C" void kernel_launch(void* const* d_in, const int* in_sizes, int n_in,
                              void* d_out, int out_size, void* d_ws, size_t ws_size,
                              hipStream_t stream) {
    const float* x   = (const float*)d_in[0];
    const float* W1  = (const float*)d_in[1];
    const float* b1  = (const float*)d_in[2];
    const float* W2  = (const float*)d_in[3];
    const float* b2  = (const float*)d_in[4];
    const float* Gw1 = (const float*)d_in[5];
    const float* Gb1 = (const float*)d_in[6];
    const float* Gw2 = (const float*)d_in[7];
    const float* Gb2 = (const float*)d_in[8];
    float* out = (float*)d_out;
    float* ws  = (float*)d_ws;   // needs 64*48*4 = 12 KB

    pack_kernel<<<1, 64, 0, stream>>>(W1, b1, W2, b2, Gw2, Gb2, ws);

    const int threads = 256;
    const int blocks = 524288 / threads;  // 2048, 1 sample/thread
    moe_kernel<<<blocks, threads, 0, stream>>>(x, ws, Gw1, Gb1, out);
}

// Round 5
// 69.305 us; speedup vs baseline: 1.2900x; 1.2900x over previous
//
#include <hip/hip_runtime.h>

// Mixture-of-64-tiny-experts, fp32.
// R4: packed-fp32 experiment. Two samples ride the two halves of
// ext_vector float2 values -> FMA chains become v_pk_fma_f32 (1 VALU inst
// per 2 samples). Trans ops (exp2/rcp) stay scalar per sample (cheap pipe).
// W2/b2 prescaled by 2*log2e, Gw2/Gb2 by log2e (pack kernel) so
// activations consume exp2-domain inputs directly.

#define NSUB 64
#define L2E2 2.8853900817779268f   // 2*log2(e)
#define L2E  1.4426950408889634f   // log2(e)

typedef float v2f __attribute__((ext_vector_type(2)));

__device__ __forceinline__ v2f pk_fma(v2f a, v2f b, v2f c) {
    return __builtin_elementwise_fma(a, b, c);
}
__device__ __forceinline__ v2f sp(float s) { return v2f{s, s}; }

// tanhshrink(a) = (a-1) + 2*rcp(exp2(2L*a)+1)   (exact formulation, fast HW ops)
__device__ __forceinline__ v2f tanhshrink_v(v2f a) {
    v2f s = a * L2E2;
    v2f e;
    e.x = __builtin_amdgcn_exp2f(s.x);
    e.y = __builtin_amdgcn_exp2f(s.y);
    v2f ep = e + 1.0f;
    v2f r;
    r.x = __builtin_amdgcn_rcpf(ep.x);
    r.y = __builtin_amdgcn_rcpf(ep.y);
    return pk_fma(sp(2.0f), r, a - 1.0f);
}

// tanh from pre-scaled input s = 2*log2e*raw: tanh = 1 - 2*rcp(exp2(s)+1)
__device__ __forceinline__ v2f tanh_scaled_v(v2f s) {
    v2f e;
    e.x = __builtin_amdgcn_exp2f(s.x);
    e.y = __builtin_amdgcn_exp2f(s.y);
    v2f ep = e + 1.0f;
    v2f r;
    r.x = __builtin_amdgcn_rcpf(ep.x);
    r.y = __builtin_amdgcn_rcpf(ep.y);
    return pk_fma(sp(-2.0f), r, sp(1.0f));
}

// Packed per-subnet params, 48 floats:
// [0:24) W1 (4x6) | [24:28) b1 | [28:36) W2*2L (2x4) | [36:38) b2*2L
// [38:44) Gw2*L | [44] Gb2*L | [45:48) pad
__global__ void pack_kernel(const float* __restrict__ W1, const float* __restrict__ b1,
                            const float* __restrict__ W2, const float* __restrict__ b2,
                            const float* __restrict__ Gw2, const float* __restrict__ Gb2,
                            float* __restrict__ ws)
{
    int s = threadIdx.x;
    if (s >= NSUB) return;
    float* f = ws + s * 48;
    for (int i = 0; i < 24; ++i) f[i]      = W1[s * 24 + i];
    for (int i = 0; i < 4;  ++i) f[24 + i] = b1[s * 4 + i];
    for (int i = 0; i < 8;  ++i) f[28 + i] = W2[s * 8 + i] * L2E2;
    for (int i = 0; i < 2;  ++i) f[36 + i] = b2[s * 2 + i] * L2E2;
    for (int i = 0; i < 6;  ++i) f[38 + i] = Gw2[s * 6 + i] * L2E;
    f[44] = Gb2[s] * L2E;
    f[45] = 0.f; f[46] = 0.f; f[47] = 0.f;
}

__global__ __launch_bounds__(256) void moe_kernel(
    const float* __restrict__ x,
    const float* __restrict__ wpack,
    const float* __restrict__ Gw1, const float* __restrict__ Gb1,
    float* __restrict__ out)
{
    int t = blockIdx.x * blockDim.x + threadIdx.x;

    // two adjacent samples per thread: 12 floats = 3 x float4 (48B-aligned)
    const float4* xv = (const float4*)(x + (long)t * 12);
    float4 a0 = xv[0];
    float4 a1 = xv[1];
    float4 a2 = xv[2];
    // xa[i] = {sampleA[i], sampleB[i]}
    v2f xa[6] = { v2f{a0.x, a1.z}, v2f{a0.y, a1.w}, v2f{a0.z, a2.x},
                  v2f{a0.w, a2.y}, v2f{a1.x, a2.z}, v2f{a1.y, a2.w} };

    // ---- gating hidden: g = tanhshrink(Gw1 @ x + Gb1) ----
    v2f ga[6];
#pragma unroll
    for (int j = 0; j < 6; ++j) {
        v2f s = sp(Gb1[j]);
#pragma unroll
        for (int i = 0; i < 6; ++i)
            s = pk_fma(sp(Gw1[j * 6 + i]), xa[i], s);
        ga[j] = tanhshrink_v(s);
    }

    // ---- subnet loop, softmax folded into running num/denom ----
    v2f acc0 = sp(0.f), acc1 = sp(0.f), accE = sp(0.f);

#pragma unroll 2
    for (int sIdx = 0; sIdx < NSUB; ++sIdx) {
        const float* f = wpack + sIdx * 48;

        v2f h[4];
#pragma unroll
        for (int j = 0; j < 4; ++j) {
            v2f s = sp(f[24 + j]);
#pragma unroll
            for (int i = 0; i < 6; ++i)
                s = pk_fma(sp(f[j * 6 + i]), xa[i], s);
            h[j] = tanhshrink_v(s);
        }

        // layer2 weights/bias pre-scaled by 2*log2e -> feed tanh_scaled
        v2f o0 = sp(f[36]), o1 = sp(f[37]);
#pragma unroll
        for (int j = 0; j < 4; ++j) {
            o0 = pk_fma(sp(f[28 + j]), h[j], o0);
            o1 = pk_fma(sp(f[32 + j]), h[j], o1);
        }
        o0 = tanh_scaled_v(o0);
        o1 = tanh_scaled_v(o1);

        // gate logit pre-scaled by log2e -> exp2 directly
        v2f la = sp(f[44]);
#pragma unroll
        for (int j = 0; j < 6; ++j)
            la = pk_fma(sp(f[38 + j]), ga[j], la);
        v2f ea;
        ea.x = __builtin_amdgcn_exp2f(la.x);
        ea.y = __builtin_amdgcn_exp2f(la.y);

        accE = accE + ea;
        acc0 = pk_fma(ea, o0, acc0);
        acc1 = pk_fma(ea, o1, acc1);
    }

    v2f ra;
    ra.x = __builtin_amdgcn_rcpf(accE.x);
    ra.y = __builtin_amdgcn_rcpf(accE.y);
    acc0 = acc0 * ra;
    acc1 = acc1 * ra;

    // out layout [B,2]; sample A = 2t, sample B = 2t+1
    float4 r;
    r.x = acc0.x; r.y = acc1.x; r.z = acc0.y; r.w = acc1.y;
    ((float4*)&out[(long)t * 4])[0] = r;
}

extern "C" void kernel_launch(void* const* d_in, const int* in_sizes, int n_in,
                              void* d_out, int out_size, void* d_ws, size_t ws_size,
                              hipStream_t stream) {
    const float* x   = (const float*)d_in[0];
    const float* W1  = (const float*)d_in[1];
    const float* b1  = (const float*)d_in[2];
    const float* W2  = (const float*)d_in[3];
    const float* b2  = (const float*)d_in[4];
    const float* Gw1 = (const float*)d_in[5];
    const float* Gb1 = (const float*)d_in[6];
    const float* Gw2 = (const float*)d_in[7];
    const float* Gb2 = (const float*)d_in[8];
    float* out = (float*)d_out;
    float* ws  = (float*)d_ws;   // 64*48*4 = 12 KB

    pack_kernel<<<1, 64, 0, stream>>>(W1, b1, W2, b2, Gw2, Gb2, ws);

    const int threads = 256;
    const int blocks = (524288 / 2) / threads;  // 1024
    moe_kernel<<<blocks, threads, 0, stream>>>(x, ws, Gw1, Gb1, out);
}